// Round 1
// baseline (33.728 us; speedup 1.0000x reference)
//
#include <hip/hip_runtime.h>

// Depth-to-space (pixel shuffle, r=8) + zero-pad to 304x304.
// out[b][c][i*8+di][j*8+dj] = x[b][c*64 + di*8 + dj][i][j]   (oh,ow < 256)
// out[...][oh>=256 or ow>=256] = 0
//
// Output-centric, one float4 store per thread. 304 % 4 == 0 so every
// float4 lies entirely in either the valid region (ow0 < 256) or the pad.

constexpr int B       = 16;
constexpr int CLASSES = 19;
constexpr int H       = 32;
constexpr int W       = 32;
constexpr int OUT     = 304;
constexpr int IN_CH   = CLASSES * 64;   // 1216
constexpr int OWQ     = OUT / 4;        // 76 float4 per output row
constexpr int TOTAL_Q = B * CLASSES * OUT * OWQ;  // 7,023,616 float4 stores

__global__ __launch_bounds__(256) void duc_kernel(const float* __restrict__ x,
                                                  float* __restrict__ out) {
    int tid = blockIdx.x * 256 + threadIdx.x;
    if (tid >= TOTAL_Q) return;

    // Decompose: tid = ((b*CLASSES + c)*OUT + oh)*OWQ + owq
    int owq = tid % OWQ;
    int q   = tid / OWQ;
    int oh  = q % OUT;
    q      /= OUT;
    int c   = q % CLASSES;
    int b   = q / CLASSES;

    int ow0 = owq * 4;

    float4 v = make_float4(0.f, 0.f, 0.f, 0.f);
    if (oh < 256 && ow0 < 256) {
        int i   = oh >> 3;
        int di  = oh & 7;
        int j   = ow0 >> 3;     // same j for all 4 elements (ow0 % 8 is 0 or 4)
        int djb = ow0 & 7;      // 0 or 4
        // channel = c*64 + di*8 + (djb + e), spatial (i, j)
        const float* base = x + (((b * IN_CH + c * 64 + di * 8 + djb) * H + i) * W + j);
        v.x = base[0 * (H * W)];
        v.y = base[1 * (H * W)];
        v.z = base[2 * (H * W)];
        v.w = base[3 * (H * W)];
    }
    reinterpret_cast<float4*>(out)[tid] = v;
}

extern "C" void kernel_launch(void* const* d_in, const int* in_sizes, int n_in,
                              void* d_out, int out_size, void* d_ws, size_t ws_size,
                              hipStream_t stream) {
    const float* x = (const float*)d_in[0];
    float* out     = (float*)d_out;
    int blocks = (TOTAL_Q + 255) / 256;   // 27,436
    duc_kernel<<<blocks, 256, 0, stream>>>(x, out);
}

// Round 3
// 32.147 us; speedup vs baseline: 1.0492x; 1.0492x over previous
//
#include <hip/hip_runtime.h>

// Depth-to-space (pixel shuffle r=8) + zero-pad to 304x304, LDS-transpose version.
//
// Main blocks: one per (b, c, i) — stage 64 channels x 32 floats (row i) in LDS
// via float4 loads (fully dense 1KiB/wave-instr), then emit 8 output rows
// (oh = i*8+di) with float4 stores. Pad cols (ow>=256) written by threads 0..95.
// Pad rows (oh>=256) zero-filled by dedicated trailing blocks.

constexpr int B       = 16;
constexpr int CLASSES = 19;
constexpr int H       = 32;
constexpr int W       = 32;
constexpr int OUT     = 304;
constexpr int IN_CH   = CLASSES * 64;          // 1216
constexpr int HW4     = (H * W) / 4;           // 256 float4 per channel
constexpr int OWQ     = OUT / 4;               // 76 float4 per output row
constexpr int NB_MAIN = B * CLASSES * H;       // 9728
constexpr int PAD_F4  = B * CLASSES * 48 * OWQ; // 1,108,992 (rows 256..303)
constexpr int NB_PAD  = PAD_F4 / 256;          // 4332 (exact)
constexpr int LSTRIDE = 36;                    // LDS floats per channel row (padded)

__global__ __launch_bounds__(256) void duc_kernel(const float* __restrict__ x,
                                                  float* __restrict__ out) {
    int t = threadIdx.x;

    if (blockIdx.x >= NB_MAIN) {
        // ---- pad rows: out[b][c][256+pr][:] = 0 ----
        int gid = (blockIdx.x - NB_MAIN) * 256 + t;     // < PAD_F4 exactly
        int bc  = gid / (48 * OWQ);
        int r4  = gid % (48 * OWQ);
        int pr  = r4 / OWQ;
        int q   = r4 % OWQ;
        reinterpret_cast<float4*>(out)[(bc * OUT + 256 + pr) * OWQ + q] =
            make_float4(0.f, 0.f, 0.f, 0.f);
        return;
    }

    __shared__ float lds[64 * LSTRIDE];   // 9216 B

    int blk = blockIdx.x;
    int b   = blk / (CLASSES * H);
    int rem = blk % (CLASSES * H);
    int c   = rem / H;
    int i   = rem % H;

    // ---- load: 64 channels x 32 floats (row i) into LDS, float4-dense ----
    const float4* x4 = reinterpret_cast<const float4*>(x);
    int ch0  = t >> 3;        // 0..31  (and ch0+32)
    int j4i  = t & 7;         // float4 index within the 32-float row
    int gbase = (b * IN_CH + c * 64) * HW4 + i * (W / 4);
    float4 v0 = x4[gbase + ch0 * HW4 + j4i];
    float4 v1 = x4[gbase + (ch0 + 32) * HW4 + j4i];
    *(reinterpret_cast<float4*>(&lds[ch0 * LSTRIDE]) + j4i) = v0;
    *(reinterpret_cast<float4*>(&lds[(ch0 + 32) * LSTRIDE]) + j4i) = v1;
    __syncthreads();

    // ---- store: 8 rows x 64 valid float4, gathered from LDS ----
    int di = t >> 5;          // 0..7
    int k  = t & 31;          // chunk id; thread handles k and k+32
    int bc = b * CLASSES + c;
    int oh = i * 8 + di;
    float4* orow = reinterpret_cast<float4*>(out) + (bc * OUT + oh) * OWQ;

#pragma unroll
    for (int s = 0; s < 2; ++s) {
        int kk  = k + s * 32;         // f4 index in row, ow0 = kk*4
        int j   = kk >> 1;            // input spatial col
        int djb = (kk & 1) * 4;       // 0 or 4
        const float* lrow = &lds[(di * 8 + djb) * LSTRIDE + j];
        float4 o;
        o.x = lrow[0 * LSTRIDE];
        o.y = lrow[1 * LSTRIDE];
        o.z = lrow[2 * LSTRIDE];
        o.w = lrow[3 * LSTRIDE];
        orow[kk] = o;
    }

    // ---- pad cols: ow 256..303 for this block's 8 rows ----
    if (t < 96) {
        int rowp = t / 12;
        int cq   = t % 12;
        reinterpret_cast<float4*>(out)[(bc * OUT + i * 8 + rowp) * OWQ + 64 + cq] =
            make_float4(0.f, 0.f, 0.f, 0.f);
    }
}

extern "C" void kernel_launch(void* const* d_in, const int* in_sizes, int n_in,
                              void* d_out, int out_size, void* d_ws, size_t ws_size,
                              hipStream_t stream) {
    const float* x = (const float*)d_in[0];
    float* out     = (float*)d_out;
    duc_kernel<<<NB_MAIN + NB_PAD, 256, 0, stream>>>(x, out);
}